// Round 5
// baseline (213.256 us; speedup 1.0000x reference)
//
#include <hip/hip_runtime.h>
#include <stdint.h>

// Problem constants (reference: B=4, S=2048, D=512, H=8, d_head=64)
#define NB  4
#define SS  2048
#define DD  512
#define HH  8
#define DHH 64
#define MM  (NB * SS)   // 8192 rows

typedef __attribute__((ext_vector_type(8))) short bf16x8;   // 8 bf16 in 4 VGPRs
typedef __attribute__((ext_vector_type(4))) float f32x4;    // 16x16 MFMA C/D
typedef __attribute__((ext_vector_type(16))) float f32x16;  // 32x32 MFMA C/D
typedef __attribute__((ext_vector_type(4))) short s16x4;    // 8 B pack

union fu32 { float f; unsigned u; };
union pfu  { uint4 u; bf16x8 v; };

// fp32 -> bf16 round-to-nearest-even (bit pattern in a short)
static __device__ __forceinline__ short f2bf(float f) {
  fu32 a; a.f = f;
  unsigned u = a.u;
  return (short)((u + 0x7fffu + ((u >> 16) & 1u)) >> 16);
}
static __device__ __forceinline__ float bf2f(short s) {
  fu32 t; t.u = ((unsigned)(unsigned short)s) << 16;
  return t.f;
}

// packed f32x2 -> bf16x2 (RNE) — no builtin on gfx950, inline asm (m240)
static __device__ __forceinline__ unsigned cvt_pk_bf16(float lo, float hi) {
  unsigned r;
  asm("v_cvt_pk_bf16_f32 %0, %1, %2" : "=v"(r) : "v"(lo), "v"(hi));
  return r;
}
// v_permlane32_swap_b32: a <- [a_lo, b_lo], b <- [a_hi, b_hi]  (VALU, not DS)
static __device__ __forceinline__ void permlane32_swap(unsigned& a, unsigned& b) {
  asm("v_permlane32_swap_b32 %0, %1" : "+v"(a), "+v"(b));
}

// async global->LDS, 16 B/lane; LDS dest = wave-uniform base + lane*16
static __device__ __forceinline__ void async16(const void* g, void* l) {
  __builtin_amdgcn_global_load_lds(
      (__attribute__((address_space(1))) unsigned*)(void*)g,
      (__attribute__((address_space(3))) unsigned*)l, 16, 0, 0);
}

// ------------------------------- prep: x->bf16 (blocks 0..2047) and
//                                 W[k][n] fp32 -> Wt[n][k] bf16 (2048..2303)
__global__ __launch_bounds__(256) void prep_kernel(
    const float* __restrict__ x, short* __restrict__ xb,
    const float* __restrict__ W0, const float* __restrict__ W1,
    const float* __restrict__ W2, const float* __restrict__ W3,
    short* __restrict__ T0, short* __restrict__ T1,
    short* __restrict__ T2, short* __restrict__ T3) {
  const int bid = blockIdx.x, tid = threadIdx.x;
  if (bid < 2048) {
    int i = (bid * 256 + tid) * 8;
    float4 v0 = *(const float4*)(x + i);
    float4 v1 = *(const float4*)(x + i + 4);
    bf16x8 o;
    o[0] = f2bf(v0.x); o[1] = f2bf(v0.y); o[2] = f2bf(v0.z); o[3] = f2bf(v0.w);
    o[4] = f2bf(v1.x); o[5] = f2bf(v1.y); o[6] = f2bf(v1.z); o[7] = f2bf(v1.w);
    *(bf16x8*)(xb + i) = o;
  } else {
    int z = bid - 2048;                 // 0..255
    int widx = z >> 6, rem = z & 63;
    const float* W = widx == 0 ? W0 : widx == 1 ? W1 : widx == 2 ? W2 : W3;
    short*       T = widx == 0 ? T0 : widx == 1 ? T1 : widx == 2 ? T2 : T3;
    int n  = (rem & 7) * 64 + (tid & 63);
    int k0 = (rem >> 3) * 64 + (tid >> 6) * 16;
    bf16x8 t0, t1;
#pragma unroll
    for (int j = 0; j < 8; ++j) t0[j] = f2bf(W[(size_t)(k0 + j) * DD + n]);
#pragma unroll
    for (int j = 0; j < 8; ++j) t1[j] = f2bf(W[(size_t)(k0 + 8 + j) * DD + n]);
    *(bf16x8*)(T + (size_t)n * DD + k0)     = t0;
    *(bf16x8*)(T + (size_t)n * DD + k0 + 8) = t1;
  }
}

// ---------------------------------------- fused QKV GEMM: 64x128, N = 1536
// grid (12,128) = 1536 blocks -> 4+ blocks/CU for latency overlap across the
// short (8-iter) K-loop.  global_load_lds staging, XOR-swizzled segments.
// Epilogue: q,k -> [B,H,S,64] bf16 (q pre-scaled), v -> [B,H,64,S] bf16.
__global__ __launch_bounds__(256, 4) void gemm_qkv_kernel(
    const short* __restrict__ A, const short* __restrict__ Bt,
    const float* __restrict__ bq, const float* __restrict__ bk,
    const float* __restrict__ bv, short* __restrict__ qout,
    short* __restrict__ kout, short* __restrict__ vtout, float qscale) {
  __shared__ __align__(16) short a_sh[64 * 64];
  __shared__ __align__(16) short b_sh[128 * 64];
  const int tid  = threadIdx.x;
  const int w    = tid >> 6, lane = tid & 63, quad = lane >> 4, l16 = lane & 15;
  const int m0   = blockIdx.y * 64, n0 = blockIdx.x * 128;
  const int mw   = (w >> 1) * 32,   nw = (w & 1) * 64;
  const int rw   = lane >> 3, seg = lane & 7, gs = seg ^ rw;  // row&7 == rw
  const int sxz  = l16 & 7;   // fragment-read swizzle key

  f32x4 acc[2][4];
#pragma unroll
  for (int i = 0; i < 2; ++i)
#pragma unroll
    for (int j = 0; j < 4; ++j) acc[i][j] = {0.f, 0.f, 0.f, 0.f};

  for (int kt = 0; kt < DD; kt += 64) {
    __syncthreads();
    {
      const short* ga = A  + (size_t)(m0 + w * 16 + rw) * DD + kt + gs * 8;
      const short* gb = Bt + (size_t)(n0 + w * 32 + rw) * DD + kt + gs * 8;
#pragma unroll
      for (int i = 0; i < 2; ++i)
        async16(ga + (size_t)i * 8 * DD, &a_sh[(w * 16 + i * 8) * 64]);
#pragma unroll
      for (int i = 0; i < 4; ++i)
        async16(gb + (size_t)i * 8 * DD, &b_sh[(w * 32 + i * 8) * 64]);
    }
    __syncthreads();
#pragma unroll
    for (int ks = 0; ks < 2; ++ks) {
      const int so = ((ks * 4 + quad) ^ sxz) * 8;
      bf16x8 af[2], bfr[4];
#pragma unroll
      for (int mt = 0; mt < 2; ++mt)
        af[mt] = *(const bf16x8*)&a_sh[(mw + mt * 16 + l16) * 64 + so];
#pragma unroll
      for (int nt = 0; nt < 4; ++nt)
        bfr[nt] = *(const bf16x8*)&b_sh[(nw + nt * 16 + l16) * 64 + so];
#pragma unroll
      for (int mt = 0; mt < 2; ++mt)
#pragma unroll
        for (int nt = 0; nt < 4; ++nt)
          acc[mt][nt] = __builtin_amdgcn_mfma_f32_16x16x32_bf16(
              af[mt], bfr[nt], acc[mt][nt], 0, 0, 0);
    }
  }

#pragma unroll
  for (int nt = 0; nt < 4; ++nt) {
    const int n   = n0 + nw + nt * 16 + l16;   // 0..1535
    const int sg  = n >> 9, n9 = n & 511, h = n9 >> 6, d = n & 63;
    const float bval = (sg == 0 ? bq : sg == 1 ? bk : bv)[n9];
    const float scl  = (sg == 0) ? qscale : 1.0f;
#pragma unroll
    for (int mt = 0; mt < 2; ++mt) {
      const int mb = m0 + mw + mt * 16 + quad * 4;   // C row = quad*4 + r
      const int bi = mb >> 11, s = mb & (SS - 1);
      if (sg == 2) {
        s16x4 pk;
#pragma unroll
        for (int r = 0; r < 4; ++r) pk[r] = f2bf(acc[mt][nt][r] + bval);
        *(s16x4*)&vtout[((size_t)(bi * HH + h) * DHH + d) * SS + s] = pk;
      } else {
        short* o = (sg == 0) ? qout : kout;
        const size_t base = ((size_t)(bi * HH + h) * SS + s) * DHH + d;
#pragma unroll
        for (int r = 0; r < 4; ++r)
          o[base + (size_t)r * DHH] = f2bf((acc[mt][nt][r] + bval) * scl);
      }
    }
  }
}

// ----------------------------------------------- flash attention, LDS-free
// Restructure: block = 64 queries x ALL 2048 keys; the 4 waves key-split
// (wave w owns keys [w*512, w*512+512)) and combine partial O / l in LDS at
// the epilogue -> no combine kernel, no partial-O HBM round trip.
// K/V for one head = 512 KB, L2-resident and XCD-local (blocks of one head
// land on one XCD via the n&7 swizzle) -> MFMA fragments are read DIRECTLY
// from global/L2: no staging, no in-loop barriers, no LDS bank conflicts.
// Fragments are bit-identical to the round-4 verified operands.  Softmax
// denominator via per-lane VALU accumulation (+ one shfl fold): saves 4
// MFMA/chunk and 30 accumulator regs.  2 Q-streams per wave (64q), 32x32x16.
__global__ __launch_bounds__(256, 3) void attn_kernel(
    const short* __restrict__ Qa, const short* __restrict__ Ka,
    const short* __restrict__ Vt, short* __restrict__ aws) {
  __shared__ float Rsh[2][64 * 68];   // two f32 reduction buffers (pad 68)
  __shared__ float l_sh[4][64];

  const int tid = threadIdx.x;
  const int w   = tid >> 6, lane = tid & 63;
  const int l32 = lane & 31, hl = lane >> 5;
  // decode: xcd = n&7; 4 (b,h) groups per XCD x 32 q-tiles -> all 32 blocks
  // of one head share an XCD L2 (K/V = 512 KB, fits 4 MB)
  const int n  = blockIdx.x;                 // 0..1023
  const int bh = (n & 7) * 4 + (n >> 8);     // 0..31
  const int qt = (n >> 3) & 31;              // 0..31
  const int h  = bh & 7, b = bh >> 3;
  const int q0 = qt * 64;
  const size_t base = (size_t)(b * HH + h) * SS * DHH;
  const short* Qg = Qa + base;
  const short* Kg = Ka + base;
  const short* Vg = Vt + base;               // [64][S]

  // Q as B-operand of 32x32x16: lane holds col(query)=l32, k(d)=ds*16+hl*8+j
  bf16x8 qf[2][4];
#pragma unroll
  for (int qx = 0; qx < 2; ++qx)
#pragma unroll
    for (int ds = 0; ds < 4; ++ds)
      qf[qx][ds] = *(const bf16x8*)(Qg + (size_t)(q0 + qx * 32 + l32) * DHH + ds * 16 + hl * 8);

  f32x16 o_acc[2][2];  // [qx][dt]: O[32q][64d], d = dt*32 + l32, rows = regs
#pragma unroll
  for (int i = 0; i < 16; ++i) {
    o_acc[0][0][i] = 0.f; o_acc[0][1][i] = 0.f;
    o_acc[1][0][i] = 0.f; o_acc[1][1][i] = 0.f;
  }
  float lsum0 = 0.f, lsum1 = 0.f;

  const int k0 = w * (SS / 4);   // this wave's 512-key range

#pragma unroll 2
  for (int kc = 0; kc < 16; ++kc) {
    const int kb = k0 + kc * 32;
    // K as A-operand: lane row(key)=kb+l32, k(d)=ds*16+hl*8+j  (direct L2)
    bf16x8 kf[4];
#pragma unroll
    for (int ds = 0; ds < 4; ++ds)
      kf[ds] = *(const bf16x8*)(Kg + (size_t)(kb + l32) * DHH + ds * 16 + hl * 8);

    f32x16 s0, s1;
#pragma unroll
    for (int i = 0; i < 16; ++i) { s0[i] = 0.f; s1[i] = 0.f; }
    __builtin_amdgcn_s_setprio(1);
#pragma unroll
    for (int ds = 0; ds < 4; ++ds) {
      s0 = __builtin_amdgcn_mfma_f32_32x32x16_bf16(kf[ds], qf[0][ds], s0, 0, 0, 0);
      s1 = __builtin_amdgcn_mfma_f32_32x32x16_bf16(kf[ds], qf[1][ds], s1, 0, 0, 0);
    }
    __builtin_amdgcn_s_setprio(0);

    // V as B-operand: lane col(d)=dt*32+l32, k(key)=kb+ks*16+hl*8+j
    bf16x8 vf[2][2];
#pragma unroll
    for (int dt = 0; dt < 2; ++dt)
#pragma unroll
      for (int ks = 0; ks < 2; ++ks)
        vf[dt][ks] = *(const bf16x8*)(Vg + (size_t)(dt * 32 + l32) * SS + kb + ks * 16 + hl * 8);

    // exp2 (q pre-scaled by log2e/8) -> per-lane l accumulate -> pack bf16
    pfu a[2][2];
#pragma unroll
    for (int qx = 0; qx < 2; ++qx) {
      f32x16& s = qx ? s1 : s0;
#pragma unroll
      for (int i = 0; i < 16; ++i) {
        s[i] = __builtin_amdgcn_exp2f(s[i]);
        if (qx) lsum1 += s[i]; else lsum0 += s[i];
      }
      unsigned wpk[8];
#pragma unroll
      for (int i = 0; i < 8; ++i) wpk[i] = cvt_pk_bf16(s[2 * i], s[2 * i + 1]);
      permlane32_swap(wpk[0], wpk[2]);
      permlane32_swap(wpk[1], wpk[3]);
      permlane32_swap(wpk[4], wpk[6]);
      permlane32_swap(wpk[5], wpk[7]);
      a[qx][0].u.x = wpk[0]; a[qx][0].u.y = wpk[1];
      a[qx][0].u.z = wpk[2]; a[qx][0].u.w = wpk[3];
      a[qx][1].u.x = wpk[4]; a[qx][1].u.y = wpk[5];
      a[qx][1].u.z = wpk[6]; a[qx][1].u.w = wpk[7];
    }

    __builtin_amdgcn_s_setprio(1);
#pragma unroll
    for (int dt = 0; dt < 2; ++dt)
#pragma unroll
      for (int ks = 0; ks < 2; ++ks) {
        o_acc[0][dt] = __builtin_amdgcn_mfma_f32_32x32x16_bf16(
            a[0][ks].v, vf[dt][ks], o_acc[0][dt], 0, 0, 0);
        o_acc[1][dt] = __builtin_amdgcn_mfma_f32_32x32x16_bf16(
            a[1][ks].v, vf[dt][ks], o_acc[1][dt], 0, 0, 0);
      }
    __builtin_amdgcn_s_setprio(0);
  }

  // ---- epilogue: cross-wave combine in LDS ------------------------------
  // fold the two hl halves: lane (l32,*) -> full per-wave l for query qx*32+l32
  lsum0 += __shfl_xor(lsum0, 32);
  lsum1 += __shfl_xor(lsum1, 32);
  if (hl == 0) { l_sh[w][l32] = lsum0; l_sh[w][32 + l32] = lsum1; }

  // o_acc reg r -> query row (r&3)+8*(r>>2)+4*hl (+qx*32), col d=dt*32+l32
  if (w < 2) {
#pragma unroll
    for (int qx = 0; qx < 2; ++qx)
#pragma unroll
      for (int dt = 0; dt < 2; ++dt)
#pragma unroll
        for (int r = 0; r < 16; ++r) {
          const int qrow = qx * 32 + (r & 3) + 8 * (r >> 2) + 4 * hl;
          Rsh[w][qrow * 68 + dt * 32 + l32] = o_acc[qx][dt][r];
        }
  }
  __syncthreads();
  if (w >= 2) {
#pragma unroll
    for (int qx = 0; qx < 2; ++qx)
#pragma unroll
      for (int dt = 0; dt < 2; ++dt)
#pragma unroll
        for (int r = 0; r < 16; ++r) {
          const int qrow = qx * 32 + (r & 3) + 8 * (r >> 2) + 4 * hl;
          const int idx  = qrow * 68 + dt * 32 + l32;
          Rsh[w - 2][idx] += o_acc[qx][dt][r];
        }
  }
  __syncthreads();

  // final: thread t -> query q = t>>2, d-chunk dc = (t&3)*16; O = (R0+R1)/l
  const int q  = tid >> 2;          // 0..63
  const int dc = (tid & 3) * 16;    // 0,16,32,48
  const float linv = __builtin_amdgcn_rcpf(
      l_sh[0][q] + l_sh[1][q] + l_sh[2][q] + l_sh[3][q]);
  bf16x8 o0, o1;
#pragma unroll
  for (int j = 0; j < 8; ++j) {
    o0[j] = f2bf((Rsh[0][q * 68 + dc + j]     + Rsh[1][q * 68 + dc + j])     * linv);
    o1[j] = f2bf((Rsh[0][q * 68 + dc + 8 + j] + Rsh[1][q * 68 + dc + 8 + j]) * linv);
  }
  short* dst = aws + ((size_t)(b * SS + q0 + q)) * DD + h * DHH + dc;
  *(bf16x8*)dst       = o0;
  *(bf16x8*)(dst + 8) = o1;
}

// ------------------------------------------- output projection: 64x64 tile
// grid (8,128) = 1024 blocks -> 4 blocks/CU.
__global__ __launch_bounds__(256, 4) void gemm_proj_kernel(
    const short* __restrict__ A, const short* __restrict__ Bt,
    const float* __restrict__ bias, float* __restrict__ out) {
  __shared__ __align__(16) short a_sh[64 * 64];
  __shared__ __align__(16) short b_sh[64 * 64];
  const int tid = threadIdx.x;
  const int w   = tid >> 6, lane = tid & 63, quad = lane >> 4, l16 = lane & 15;
  const int m0  = blockIdx.y * 64, n0 = blockIdx.x * 64;
  const int mw  = (w >> 1) * 32, nw = (w & 1) * 32;
  const int rw  = lane >> 3, seg = lane & 7, gs = seg ^ rw;
  const int sxz = l16 & 7;

  f32x4 acc[2][2];
#pragma unroll
  for (int i = 0; i < 2; ++i)
#pragma unroll
    for (int j = 0; j < 2; ++j) acc[i][j] = {0.f, 0.f, 0.f, 0.f};

  for (int kt = 0; kt < DD; kt += 64) {
    __syncthreads();
    {
      const short* ga = A  + (size_t)(m0 + w * 16 + rw) * DD + kt + gs * 8;
      const short* gb = Bt + (size_t)(n0 + w * 16 + rw) * DD + kt + gs * 8;
#pragma unroll
      for (int i = 0; i < 2; ++i) {
        async16(ga + (size_t)i * 8 * DD, &a_sh[(w * 16 + i * 8) * 64]);
        async16(gb + (size_t)i * 8 * DD, &b_sh[(w * 16 + i * 8) * 64]);
      }
    }
    __syncthreads();
#pragma unroll
    for (int ks = 0; ks < 2; ++ks) {
      const int so = ((ks * 4 + quad) ^ sxz) * 8;
      bf16x8 af0 = *(const bf16x8*)&a_sh[(mw + l16) * 64 + so];
      bf16x8 af1 = *(const bf16x8*)&a_sh[(mw + 16 + l16) * 64 + so];
#pragma unroll
      for (int nt = 0; nt < 2; ++nt) {
        bf16x8 bfr = *(const bf16x8*)&b_sh[(nw + nt * 16 + l16) * 64 + so];
        acc[0][nt] = __builtin_amdgcn_mfma_f32_16x16x32_bf16(af0, bfr, acc[0][nt], 0, 0, 0);
        acc[1][nt] = __builtin_amdgcn_mfma_f32_16x16x32_bf16(af1, bfr, acc[1][nt], 0, 0, 0);
      }
    }
  }

#pragma unroll
  for (int nt = 0; nt < 2; ++nt) {
    const int   n  = n0 + nw + nt * 16 + l16;
    const float bv = bias[n];
#pragma unroll
    for (int mt = 0; mt < 2; ++mt)
#pragma unroll
      for (int r = 0; r < 4; ++r) {
        const int m = m0 + mw + mt * 16 + quad * 4 + r;
        out[(size_t)m * DD + n] = acc[mt][nt][r] + bv;
      }
  }
}

// ---------------------------------------------------------------- launcher
extern "C" void kernel_launch(void* const* d_in, const int* in_sizes, int n_in,
                              void* d_out, int out_size, void* d_ws, size_t ws_size,
                              hipStream_t stream) {
  (void)in_sizes; (void)n_in; (void)out_size; (void)ws_size;
  const float* x  = (const float*)d_in[0];
  const float* Wq = (const float*)d_in[1];
  const float* bq = (const float*)d_in[2];
  const float* Wk = (const float*)d_in[3];
  const float* bk = (const float*)d_in[4];
  const float* Wv = (const float*)d_in[5];
  const float* bv = (const float*)d_in[6];
  const float* Wh = (const float*)d_in[7];
  const float* bh = (const float*)d_in[8];

  short* ws  = (short*)d_ws;
  short* xb  = ws;                              // x bf16 [8192,512]
  short* wqt = xb  + (size_t)MM * DD;           // Wq^T bf16 [512,512]
  short* wkt = wqt + (size_t)DD * DD;           // (wqt..wvt contiguous = QKV Bt)
  short* wvt = wkt + (size_t)DD * DD;
  short* wht = wvt + (size_t)DD * DD;
  short* qws = wht + (size_t)DD * DD;           // q bf16 [B,H,S,64] (pre-scaled)
  short* kws = qws + (size_t)MM * DD;           // k bf16 [B,H,S,64]
  short* vws = kws + (size_t)MM * DD;           // v^T bf16 [B,H,64,S]
  short* aws = vws + (size_t)MM * DD;           // attn out bf16 [B,S,512]

  hipLaunchKernelGGL(prep_kernel, dim3(2048 + 256), dim3(256), 0, stream,
                     x, xb, Wq, Wk, Wv, Wh, wqt, wkt, wvt, wht);

  // q pre-scale: (1/sqrt(64)) * log2(e) so softmax uses exp2 directly
  const float qscale = 1.4426950408889634f / 8.0f;
  hipLaunchKernelGGL(gemm_qkv_kernel, dim3(12, 128), dim3(256), 0, stream,
                     xb, wqt, bq, bk, bv, qws, kws, vws, qscale);

  hipLaunchKernelGGL(attn_kernel, dim3(1024), dim3(256), 0, stream,
                     qws, kws, vws, aws);

  hipLaunchKernelGGL(gemm_proj_kernel, dim3(8, 128), dim3(256), 0, stream,
                     aws, wht, bh, (float*)d_out);
}